// Round 2
// baseline (5839.209 us; speedup 1.0000x reference)
//
#include <hip/hip_runtime.h>
#include <cstdint>
#include <cstddef>

#define D_ 512
#define S_ 25
#define H_ 16
#define HD_ 32
#define DEPTH_ 3
#define NG_ 250
#define BATCH_ 4096
#define M_ (BATCH_ * S_) /* 102400 */
#define EPS_ 1e-5f

typedef __attribute__((ext_vector_type(8))) short short8;
typedef __attribute__((ext_vector_type(4))) short short4v;
typedef __attribute__((ext_vector_type(4))) float f32x4;

__device__ __forceinline__ float b2f(short s) {
  union { unsigned u; float f; } c;
  c.u = ((unsigned)(unsigned short)s) << 16;
  return c.f;
}
__device__ __forceinline__ short f2b(float f) {
  union { float f; unsigned u; } c; c.f = f;
  unsigned u = c.u + 0x7FFFu + ((c.u >> 16) & 1u);
  return (short)(u >> 16);
}

__device__ __forceinline__ void gld_lds16(const void* g, void* l) {
  __builtin_amdgcn_global_load_lds((const __attribute__((address_space(1))) void*)g,
                                   (__attribute__((address_space(3))) void*)l, 16, 0, 0);
}

// ---------------------------------------------------------------------------
// f32 -> bf16 conversion (weights), 4 elems/thread
// ---------------------------------------------------------------------------
__global__ __launch_bounds__(256) void cvt_f2b_ker(const float* __restrict__ in,
                                                   short* __restrict__ out, int n4) {
  int i = blockIdx.x * 256 + threadIdx.x;
  if (i < n4) {
    f32x4 v = *(const f32x4*)(in + (size_t)i * 4);
    short4v o;
#pragma unroll
    for (int j = 0; j < 4; ++j) o[j] = f2b(v[j]);
    *(short4v*)(out + (size_t)i * 4) = o;
  }
}

// ---------------------------------------------------------------------------
// LayerNorm: one wave per 512-row. bf16 output variant (for GEMM A input).
// ---------------------------------------------------------------------------
__global__ __launch_bounds__(256) void ln_to_bf16_ker(const float* __restrict__ x,
                                                      const float* __restrict__ g,
                                                      const float* __restrict__ bb,
                                                      short* __restrict__ out) {
  int row = (blockIdx.x << 2) + (threadIdx.x >> 6);
  int l = threadIdx.x & 63;
  const float* xr = x + (size_t)row * D_ + l * 8;
  f32x4 a = *(const f32x4*)xr;
  f32x4 b2v = *(const f32x4*)(xr + 4);
  float v[8];
#pragma unroll
  for (int j = 0; j < 4; ++j) { v[j] = a[j]; v[j + 4] = b2v[j]; }
  float s = 0.f, q = 0.f;
#pragma unroll
  for (int j = 0; j < 8; ++j) { s += v[j]; q += v[j] * v[j]; }
#pragma unroll
  for (int off = 32; off; off >>= 1) { s += __shfl_xor(s, off); q += __shfl_xor(q, off); }
  float mean = s * (1.0f / 512.0f);
  float var = q * (1.0f / 512.0f) - mean * mean;
  float rstd = rsqrtf(var + EPS_);
  const float* gp = g + l * 8;
  const float* bp = bb + l * 8;
  f32x4 g0 = *(const f32x4*)gp, g1 = *(const f32x4*)(gp + 4);
  f32x4 b0 = *(const f32x4*)bp, b1 = *(const f32x4*)(bp + 4);
  short8 o;
#pragma unroll
  for (int j = 0; j < 8; ++j) {
    float gg = (j < 4) ? g0[j] : g1[j - 4];
    float bv = (j < 4) ? b0[j] : b1[j - 4];
    o[j] = f2b((v[j] - mean) * rstd * gg + bv);
  }
  *(short8*)(out + (size_t)row * D_ + l * 8) = o;
}

// f32 in-place variant (final LN on d_out x region)
__global__ __launch_bounds__(256) void ln_f32_inplace_ker(float* __restrict__ x,
                                                          const float* __restrict__ g,
                                                          const float* __restrict__ bb) {
  int row = (blockIdx.x << 2) + (threadIdx.x >> 6);
  int l = threadIdx.x & 63;
  float* xr = x + (size_t)row * D_ + l * 8;
  f32x4 a = *(const f32x4*)xr;
  f32x4 b2v = *(const f32x4*)(xr + 4);
  float v[8];
#pragma unroll
  for (int j = 0; j < 4; ++j) { v[j] = a[j]; v[j + 4] = b2v[j]; }
  float s = 0.f, q = 0.f;
#pragma unroll
  for (int j = 0; j < 8; ++j) { s += v[j]; q += v[j] * v[j]; }
#pragma unroll
  for (int off = 32; off; off >>= 1) { s += __shfl_xor(s, off); q += __shfl_xor(q, off); }
  float mean = s * (1.0f / 512.0f);
  float var = q * (1.0f / 512.0f) - mean * mean;
  float rstd = rsqrtf(var + EPS_);
  const float* gp = g + l * 8;
  const float* bp = bb + l * 8;
  f32x4 g0 = *(const f32x4*)gp, g1 = *(const f32x4*)(gp + 4);
  f32x4 b0 = *(const f32x4*)bp, b1 = *(const f32x4*)(bp + 4);
  f32x4 o0, o1;
#pragma unroll
  for (int j = 0; j < 4; ++j) {
    o0[j] = (v[j] - mean) * rstd * g0[j] + b0[j];
    o1[j] = (v[j + 4] - mean) * rstd * g1[j] + b1[j];
  }
  *(f32x4*)xr = o0;
  *(f32x4*)(xr + 4) = o1;
}

// ---------------------------------------------------------------------------
// bf16 GEMM: out[m][n] = sum_k A[m][k] * W[n][k] + bias[n]   (K = 512 fixed)
// 128x128 tile, BK=64, 4 waves (2x2), mfma_f32_16x16x32_bf16, XOR-swizzled LDS,
// global_load_lds width-16 staging. 1-D grid + bijective XCD-chunked swizzle
// (nwg % 8 == 0) so n-tiles sharing an A-stripe land on the same XCD L2.
// EPI: 0 = store bf16, 1 = f32 residual add into Xres,
//      2 = exact GELU -> bf16, 3 = Xres = Xbase + v (first residual)
// ---------------------------------------------------------------------------
template <int EPI>
__global__ __launch_bounds__(256) void gemm_bf16_ker(const short* __restrict__ A,
                                                     const short* __restrict__ Bw,
                                                     const float* __restrict__ bias,
                                                     short* __restrict__ Obf,
                                                     float* __restrict__ Xres,
                                                     const float* __restrict__ Xbase,
                                                     int N, int nx) {
  constexpr int K = 512;
  __shared__ short At[128 * 64];
  __shared__ short Bt[128 * 64];
  const int tid = threadIdx.x;
  const int l = tid & 63;
  const int w = tid >> 6;
  const int wr = w >> 1, wc = w & 1;
  // XCD-chunked bijective swizzle (gridDim.x % 8 == 0)
  const int nwg = gridDim.x;
  const int orig = blockIdx.x;
  const int wg = ((orig & 7) * (nwg >> 3)) + (orig >> 3);
  const int by = wg / nx;
  const int bx = wg - by * nx;
  const int m0 = by * 128;
  const int n0 = bx * 128;

  f32x4 acc[4][4] = {};

  for (int kt = 0; kt < K; kt += 64) {
#pragma unroll
    for (int i = 0; i < 4; ++i) {
      int chunk = i * 256 + tid;
      int row = chunk >> 3;
      int colS = ((chunk & 7) << 3) ^ ((row & 7) << 3);  // swizzled source col (shorts)
      const short* ga = A + (size_t)(m0 + row) * K + kt + colS;
      const short* gb = Bw + (size_t)(n0 + row) * K + kt + colS;
      int base = (i * 256 + (w << 6)) << 3;  // wave-uniform LDS base (shorts)
      gld_lds16(ga, &At[base]);
      gld_lds16(gb, &Bt[base]);
    }
    __syncthreads();
#pragma unroll
    for (int kk = 0; kk < 64; kk += 32) {
      short8 af[4], bfr[4];
#pragma unroll
      for (int mi = 0; mi < 4; ++mi) {
        int row = (wr << 6) + (mi << 4) + (l & 15);
        int colS = (kk + ((l >> 4) << 3)) ^ ((row & 7) << 3);
        af[mi] = *(const short8*)&At[row * 64 + colS];
      }
#pragma unroll
      for (int ni = 0; ni < 4; ++ni) {
        int row = (wc << 6) + (ni << 4) + (l & 15);
        int colS = (kk + ((l >> 4) << 3)) ^ ((row & 7) << 3);
        bfr[ni] = *(const short8*)&Bt[row * 64 + colS];
      }
#pragma unroll
      for (int mi = 0; mi < 4; ++mi)
#pragma unroll
        for (int ni = 0; ni < 4; ++ni)
          acc[mi][ni] = __builtin_amdgcn_mfma_f32_16x16x32_bf16(af[mi], bfr[ni], acc[mi][ni], 0, 0, 0);
    }
    __syncthreads();
  }

  const int lrow = (l >> 4) << 2;  // +reg -> row within 16
  const int lcol = l & 15;
#pragma unroll
  for (int ni = 0; ni < 4; ++ni) {
    int gn = n0 + (wc << 6) + (ni << 4) + lcol;
    float bs = bias[gn];
#pragma unroll
    for (int mi = 0; mi < 4; ++mi) {
      int gm = m0 + (wr << 6) + (mi << 4) + lrow;
#pragma unroll
      for (int r = 0; r < 4; ++r) {
        float v = acc[mi][ni][r] + bs;
        size_t idx = (size_t)(gm + r) * N + gn;
        if (EPI == 0) {
          Obf[idx] = f2b(v);
        } else if (EPI == 1) {
          Xres[idx] += v;
        } else if (EPI == 2) {
          Obf[idx] = f2b(0.5f * v * (1.0f + erff(v * 0.70710678118654752f)));
        } else {
          Xres[idx] = Xbase[idx] + v;
        }
      }
    }
  }
}

// ---------------------------------------------------------------------------
// Per-(cell,head,query) attention. No LDS, no barriers: K/V slices are L2-hot
// (just produced by the QKV GEMM) and all 25 lanes of an (h,.) group read the
// SAME K/V address -> L1 broadcast. qkv row layout [token][1536]:
// q[0:512], k[512:1024], v[1024:1536], channel c = h*32+d.
// ---------------------------------------------------------------------------
__global__ __launch_bounds__(256) void attn_ker(const short* __restrict__ qkv,
                                                const float* __restrict__ bias_table,
                                                short* __restrict__ o) {
  unsigned p = blockIdx.x * 256 + threadIdx.x;  // < 4096*400 (grid = 6400)
  unsigned b = p / 400u;
  unsigned r = p - b * 400u;
  unsigned h = r / 25u;
  unsigned i = r - h * 25u;
  const short* cell = qkv + (size_t)b * S_ * 1536;
  const short* qp = cell + (size_t)i * 1536 + h * HD_;
  float q[HD_];
#pragma unroll
  for (int c = 0; c < 4; ++c) {
    short8 v = *(const short8*)(qp + c * 8);
#pragma unroll
    for (int jj = 0; jj < 8; ++jj) q[c * 8 + jj] = b2f(v[jj]);
  }
  const float scale = 0.17677669529663687f;  // 1/sqrt(32)
  int xi = i / 5, yi = i - xi * 5;
  float sc[S_];
  float mx = -1e30f;
#pragma unroll
  for (int j = 0; j < S_; ++j) {
    const short* kp = cell + (size_t)j * 1536 + 512 + h * HD_;
    float s = 0.f;
#pragma unroll
    for (int c = 0; c < 4; ++c) {
      short8 v = *(const short8*)(kp + c * 8);
#pragma unroll
      for (int jj = 0; jj < 8; ++jj) s += q[c * 8 + jj] * b2f(v[jj]);
    }
    int xj = j / 5, yj = j - xj * 5;
    int ridx = (xi - xj + 4) * 9 + (yi - yj + 4);
    s = s * scale + bias_table[ridx * H_ + h];
    sc[j] = s;
    mx = fmaxf(mx, s);
  }
  float den = 0.f;
#pragma unroll
  for (int j = 0; j < S_; ++j) {
    float e = __expf(sc[j] - mx);
    sc[j] = e;
    den += e;
  }
  float inv = 1.0f / den;
  float ov[HD_];
#pragma unroll
  for (int d = 0; d < HD_; ++d) ov[d] = 0.f;
#pragma unroll
  for (int j = 0; j < S_; ++j) {
    float pr = sc[j] * inv;
    const short* vp = cell + (size_t)j * 1536 + 1024 + h * HD_;
#pragma unroll
    for (int c = 0; c < 4; ++c) {
      short8 v = *(const short8*)(vp + c * 8);
#pragma unroll
      for (int jj = 0; jj < 8; ++jj) ov[c * 8 + jj] += pr * b2f(v[jj]);
    }
  }
  short* op = o + ((size_t)b * S_ + i) * D_ + h * HD_;
#pragma unroll
  for (int c = 0; c < 4; ++c) {
    short8 v;
#pragma unroll
    for (int jj = 0; jj < 8; ++jj) v[jj] = f2b(ov[c * 8 + jj]);
    *(short8*)(op + c * 8) = v;
  }
}

// ---------------------------------------------------------------------------
// Mean-pool over S then pred head: pred[b][n] = pooled . pred_w[n] + pred_b[n]
// ---------------------------------------------------------------------------
__global__ __launch_bounds__(256) void pred_ker(const float* __restrict__ xf,
                                                const float* __restrict__ pw,
                                                const float* __restrict__ pb,
                                                float* __restrict__ pred) {
  __shared__ float pooled[D_];
  int b = blockIdx.x;
  const float* xb = xf + (size_t)b * S_ * D_;
  for (int d = threadIdx.x; d < D_; d += 256) {
    float s = 0.f;
#pragma unroll
    for (int j = 0; j < S_; ++j) s += xb[(size_t)j * D_ + d];
    pooled[d] = s * (1.0f / 25.0f);
  }
  __syncthreads();
  for (int n = threadIdx.x; n < NG_; n += 256) {
    const float* w = pw + (size_t)n * D_;
    float s = pb[n];
    for (int d = 0; d < D_; d += 4) {
      f32x4 wv = *(const f32x4*)(w + d);
      s += pooled[d] * wv[0] + pooled[d + 1] * wv[1] + pooled[d + 2] * wv[2] +
           pooled[d + 3] * wv[3];
    }
    pred[(size_t)b * NG_ + n] = s;
  }
}

// ---------------------------------------------------------------------------
extern "C" void kernel_launch(void* const* d_in, const int* in_sizes, int n_in,
                              void* d_out, int out_size, void* d_ws, size_t ws_size,
                              hipStream_t stream) {
  const float* nf = (const float*)d_in[0];
  const float* bias_table = (const float*)d_in[1];
  const float* ln1_g = (const float*)d_in[2];
  const float* ln1_b = (const float*)d_in[3];
  const float* wqkv = (const float*)d_in[4];
  const float* bqkv = (const float*)d_in[5];
  const float* wo = (const float*)d_in[6];
  const float* bo = (const float*)d_in[7];
  const float* ln2_g = (const float*)d_in[8];
  const float* ln2_b = (const float*)d_in[9];
  const float* w1 = (const float*)d_in[10];
  const float* b1 = (const float*)d_in[11];
  const float* w2 = (const float*)d_in[12];
  const float* b2 = (const float*)d_in[13];
  const float* lnf_g = (const float*)d_in[14];
  const float* lnf_b = (const float*)d_in[15];
  const float* pred_w = (const float*)d_in[16];
  const float* pred_b = (const float*)d_in[17];

  float* x = (float*)d_out;                 // residual stream lives in d_out x-region
  float* pred = x + (size_t)M_ * D_;        // [4096][250]

  char* p = (char*)d_ws;
  short* qkvb = (short*)p; p += (size_t)M_ * 1536 * 2;
  short* xnb = (short*)p;  p += (size_t)M_ * D_ * 2;
  short* ob = (short*)p;   p += (size_t)M_ * D_ * 2;
  short* hb = (short*)p;   p += (size_t)M_ * D_ * 2;
  short* wqkvb = (short*)p; p += (size_t)DEPTH_ * 1536 * 512 * 2;
  short* wob = (short*)p;   p += (size_t)DEPTH_ * 512 * 512 * 2;
  short* w1b = (short*)p;   p += (size_t)DEPTH_ * 512 * 512 * 2;
  short* w2b = (short*)p;   p += (size_t)DEPTH_ * 512 * 512 * 2;

  // weights -> bf16
  {
    int n4 = DEPTH_ * 1536 * 512 / 4;
    cvt_f2b_ker<<<(n4 + 255) / 256, 256, 0, stream>>>(wqkv, wqkvb, n4);
    n4 = DEPTH_ * 512 * 512 / 4;
    cvt_f2b_ker<<<(n4 + 255) / 256, 256, 0, stream>>>(wo, wob, n4);
    cvt_f2b_ker<<<(n4 + 255) / 256, 256, 0, stream>>>(w1, w1b, n4);
    cvt_f2b_ker<<<(n4 + 255) / 256, 256, 0, stream>>>(w2, w2b, n4);
  }

  for (int L = 0; L < DEPTH_; ++L) {
    const float* xin = (L == 0) ? nf : x;
    // LN1 -> xn (bf16)
    ln_to_bf16_ker<<<M_ / 4, 256, 0, stream>>>(xin, ln1_g + L * D_, ln1_b + L * D_, xnb);
    // qkv = xn @ wqkv^T + bqkv (bf16 out)
    gemm_bf16_ker<0><<<(1536 / 128) * (M_ / 128), 256, 0, stream>>>(
        xnb, wqkvb + (size_t)L * 1536 * 512, bqkv + (size_t)L * 1536, qkvb, nullptr,
        nullptr, 1536, 12);
    // attention -> o (bf16)
    attn_ker<<<BATCH_ * 400 / 256, 256, 0, stream>>>(qkvb, bias_table, ob);
    // x += o @ wo^T + bo   (layer 0: x = nf + o @ wo^T + bo, kills the memcpy)
    if (L == 0) {
      gemm_bf16_ker<3><<<(512 / 128) * (M_ / 128), 256, 0, stream>>>(
          ob, wob, bo, nullptr, x, nf, 512, 4);
    } else {
      gemm_bf16_ker<1><<<(512 / 128) * (M_ / 128), 256, 0, stream>>>(
          ob, wob + (size_t)L * 512 * 512, bo + (size_t)L * D_, nullptr, x, nullptr, 512, 4);
    }
    // LN2 -> xn
    ln_to_bf16_ker<<<M_ / 4, 256, 0, stream>>>(x, ln2_g + L * D_, ln2_b + L * D_, xnb);
    // h = gelu(xn @ w1^T + b1) (bf16 out)
    gemm_bf16_ker<2><<<(512 / 128) * (M_ / 128), 256, 0, stream>>>(
        xnb, w1b + (size_t)L * 512 * 512, b1 + (size_t)L * D_, hb, nullptr, nullptr, 512, 4);
    // x += h @ w2^T + b2
    gemm_bf16_ker<1><<<(512 / 128) * (M_ / 128), 256, 0, stream>>>(
        hb, w2b + (size_t)L * 512 * 512, b2 + (size_t)L * D_, nullptr, x, nullptr, 512, 4);
  }

  // final LN in place on d_out x region
  ln_f32_inplace_ker<<<M_ / 4, 256, 0, stream>>>(x, lnf_g, lnf_b);
  // pooled mean + pred head
  pred_ker<<<BATCH_, 256, 0, stream>>>(x, pred_w, pred_b, pred);
}

// Round 3
// 5264.722 us; speedup vs baseline: 1.1091x; 1.1091x over previous
//
#include <hip/hip_runtime.h>
#include <cstdint>
#include <cstddef>

#define D_ 512
#define S_ 25
#define H_ 16
#define HD_ 32
#define DEPTH_ 3
#define NG_ 250
#define BATCH_ 4096
#define M_ (BATCH_ * S_) /* 102400 */
#define EPS_ 1e-5f

typedef __attribute__((ext_vector_type(8))) short short8;
typedef __attribute__((ext_vector_type(4))) short short4v;
typedef __attribute__((ext_vector_type(4))) float f32x4;

__device__ __forceinline__ float b2f(short s) {
  union { unsigned u; float f; } c;
  c.u = ((unsigned)(unsigned short)s) << 16;
  return c.f;
}
__device__ __forceinline__ short f2b(float f) {
  union { float f; unsigned u; } c; c.f = f;
  unsigned u = c.u + 0x7FFFu + ((c.u >> 16) & 1u);
  return (short)(u >> 16);
}

__device__ __forceinline__ void gld_lds16(const void* g, void* l) {
  __builtin_amdgcn_global_load_lds((const __attribute__((address_space(1))) void*)g,
                                   (__attribute__((address_space(3))) void*)l, 16, 0, 0);
}

// ---------------------------------------------------------------------------
// f32 -> bf16 conversion (weights), 4 elems/thread
// ---------------------------------------------------------------------------
__global__ __launch_bounds__(256) void cvt_f2b_ker(const float* __restrict__ in,
                                                   short* __restrict__ out, int n4) {
  int i = blockIdx.x * 256 + threadIdx.x;
  if (i < n4) {
    f32x4 v = *(const f32x4*)(in + (size_t)i * 4);
    short4v o;
#pragma unroll
    for (int j = 0; j < 4; ++j) o[j] = f2b(v[j]);
    *(short4v*)(out + (size_t)i * 4) = o;
  }
}

// ---------------------------------------------------------------------------
// LayerNorm: one wave per 512-row. bf16 output variant (for GEMM A input).
// ---------------------------------------------------------------------------
__global__ __launch_bounds__(256) void ln_to_bf16_ker(const float* __restrict__ x,
                                                      const float* __restrict__ g,
                                                      const float* __restrict__ bb,
                                                      short* __restrict__ out) {
  int row = (blockIdx.x << 2) + (threadIdx.x >> 6);
  int l = threadIdx.x & 63;
  const float* xr = x + (size_t)row * D_ + l * 8;
  f32x4 a = *(const f32x4*)xr;
  f32x4 b2v = *(const f32x4*)(xr + 4);
  float v[8];
#pragma unroll
  for (int j = 0; j < 4; ++j) { v[j] = a[j]; v[j + 4] = b2v[j]; }
  float s = 0.f, q = 0.f;
#pragma unroll
  for (int j = 0; j < 8; ++j) { s += v[j]; q += v[j] * v[j]; }
#pragma unroll
  for (int off = 32; off; off >>= 1) { s += __shfl_xor(s, off); q += __shfl_xor(q, off); }
  float mean = s * (1.0f / 512.0f);
  float var = q * (1.0f / 512.0f) - mean * mean;
  float rstd = rsqrtf(var + EPS_);
  const float* gp = g + l * 8;
  const float* bp = bb + l * 8;
  f32x4 g0 = *(const f32x4*)gp, g1 = *(const f32x4*)(gp + 4);
  f32x4 b0 = *(const f32x4*)bp, b1 = *(const f32x4*)(bp + 4);
  short8 o;
#pragma unroll
  for (int j = 0; j < 8; ++j) {
    float gg = (j < 4) ? g0[j] : g1[j - 4];
    float bv = (j < 4) ? b0[j] : b1[j - 4];
    o[j] = f2b((v[j] - mean) * rstd * gg + bv);
  }
  *(short8*)(out + (size_t)row * D_ + l * 8) = o;
}

// f32 in-place variant (final LN on d_out x region)
__global__ __launch_bounds__(256) void ln_f32_inplace_ker(float* __restrict__ x,
                                                          const float* __restrict__ g,
                                                          const float* __restrict__ bb) {
  int row = (blockIdx.x << 2) + (threadIdx.x >> 6);
  int l = threadIdx.x & 63;
  float* xr = x + (size_t)row * D_ + l * 8;
  f32x4 a = *(const f32x4*)xr;
  f32x4 b2v = *(const f32x4*)(xr + 4);
  float v[8];
#pragma unroll
  for (int j = 0; j < 4; ++j) { v[j] = a[j]; v[j + 4] = b2v[j]; }
  float s = 0.f, q = 0.f;
#pragma unroll
  for (int j = 0; j < 8; ++j) { s += v[j]; q += v[j] * v[j]; }
#pragma unroll
  for (int off = 32; off; off >>= 1) { s += __shfl_xor(s, off); q += __shfl_xor(q, off); }
  float mean = s * (1.0f / 512.0f);
  float var = q * (1.0f / 512.0f) - mean * mean;
  float rstd = rsqrtf(var + EPS_);
  const float* gp = g + l * 8;
  const float* bp = bb + l * 8;
  f32x4 g0 = *(const f32x4*)gp, g1 = *(const f32x4*)(gp + 4);
  f32x4 b0 = *(const f32x4*)bp, b1 = *(const f32x4*)(bp + 4);
  f32x4 o0, o1;
#pragma unroll
  for (int j = 0; j < 4; ++j) {
    o0[j] = (v[j] - mean) * rstd * g0[j] + b0[j];
    o1[j] = (v[j + 4] - mean) * rstd * g1[j] + b1[j];
  }
  *(f32x4*)xr = o0;
  *(f32x4*)(xr + 4) = o1;
}

// ---------------------------------------------------------------------------
// bf16 GEMM: out[m][n] = sum_k A[m][k] * W[n][k] + bias[n]   (K = 512 fixed)
// 128x128 tile, BK=64, 4 waves (2x2), mfma_f32_16x16x32_bf16, XOR-swizzled LDS,
// global_load_lds width-16 staging. 1-D grid + bijective XCD-chunked swizzle
// (nwg % 8 == 0) so n-tiles sharing an A-stripe land on the same XCD L2.
// EPI: 0 = store bf16, 1 = f32 residual add into Xres,
//      2 = exact GELU -> bf16, 3 = Xres = Xbase + v (first residual)
// ---------------------------------------------------------------------------
template <int EPI>
__global__ __launch_bounds__(256) void gemm_bf16_ker(const short* __restrict__ A,
                                                     const short* __restrict__ Bw,
                                                     const float* __restrict__ bias,
                                                     short* __restrict__ Obf,
                                                     float* __restrict__ Xres,
                                                     const float* __restrict__ Xbase,
                                                     int N, int nx) {
  constexpr int K = 512;
  __shared__ short At[128 * 64];
  __shared__ short Bt[128 * 64];
  const int tid = threadIdx.x;
  const int l = tid & 63;
  const int w = tid >> 6;
  const int wr = w >> 1, wc = w & 1;
  // XCD-chunked bijective swizzle (gridDim.x % 8 == 0)
  const int nwg = gridDim.x;
  const int orig = blockIdx.x;
  const int wg = ((orig & 7) * (nwg >> 3)) + (orig >> 3);
  const int by = wg / nx;
  const int bx = wg - by * nx;
  const int m0 = by * 128;
  const int n0 = bx * 128;

  f32x4 acc[4][4] = {};

  for (int kt = 0; kt < K; kt += 64) {
#pragma unroll
    for (int i = 0; i < 4; ++i) {
      int chunk = i * 256 + tid;
      int row = chunk >> 3;
      int colS = ((chunk & 7) << 3) ^ ((row & 7) << 3);  // swizzled source col (shorts)
      const short* ga = A + (size_t)(m0 + row) * K + kt + colS;
      const short* gb = Bw + (size_t)(n0 + row) * K + kt + colS;
      int base = (i * 256 + (w << 6)) << 3;  // wave-uniform LDS base (shorts)
      gld_lds16(ga, &At[base]);
      gld_lds16(gb, &Bt[base]);
    }
    __syncthreads();
#pragma unroll
    for (int kk = 0; kk < 64; kk += 32) {
      short8 af[4], bfr[4];
#pragma unroll
      for (int mi = 0; mi < 4; ++mi) {
        int row = (wr << 6) + (mi << 4) + (l & 15);
        int colS = (kk + ((l >> 4) << 3)) ^ ((row & 7) << 3);
        af[mi] = *(const short8*)&At[row * 64 + colS];
      }
#pragma unroll
      for (int ni = 0; ni < 4; ++ni) {
        int row = (wc << 6) + (ni << 4) + (l & 15);
        int colS = (kk + ((l >> 4) << 3)) ^ ((row & 7) << 3);
        bfr[ni] = *(const short8*)&Bt[row * 64 + colS];
      }
#pragma unroll
      for (int mi = 0; mi < 4; ++mi)
#pragma unroll
        for (int ni = 0; ni < 4; ++ni)
          acc[mi][ni] = __builtin_amdgcn_mfma_f32_16x16x32_bf16(af[mi], bfr[ni], acc[mi][ni], 0, 0, 0);
    }
    __syncthreads();
  }

  const int lrow = (l >> 4) << 2;  // +reg -> row within 16
  const int lcol = l & 15;
#pragma unroll
  for (int ni = 0; ni < 4; ++ni) {
    int gn = n0 + (wc << 6) + (ni << 4) + lcol;
    float bs = bias[gn];
#pragma unroll
    for (int mi = 0; mi < 4; ++mi) {
      int gm = m0 + (wr << 6) + (mi << 4) + lrow;
#pragma unroll
      for (int r = 0; r < 4; ++r) {
        float v = acc[mi][ni][r] + bs;
        size_t idx = (size_t)(gm + r) * N + gn;
        if (EPI == 0) {
          Obf[idx] = f2b(v);
        } else if (EPI == 1) {
          Xres[idx] += v;
        } else if (EPI == 2) {
          Obf[idx] = f2b(0.5f * v * (1.0f + erff(v * 0.70710678118654752f)));
        } else {
          Xres[idx] = Xbase[idx] + v;
        }
      }
    }
  }
}

// ---------------------------------------------------------------------------
// Attention: block = 256 threads = 4 waves = 4 heads of one cell.
// K/V for those heads staged in LDS (12.8 KB -> 8 blocks/CU).
// Wave lane = (query i, d-half): lanes 0..49 active; score halves combined
// via __shfl_xor(s,1). qkv row layout [token][1536]: q[0:512], k[512:1024],
// v[1024:1536], channel c = h*32+d.
// ---------------------------------------------------------------------------
__global__ __launch_bounds__(256) void attn_ker(const short* __restrict__ qkv,
                                                const float* __restrict__ bias_table,
                                                short* __restrict__ o) {
  __shared__ short kv[2][S_ * 128];  // [k/v][token][4 heads * 32 ch]
  const int blk = blockIdx.x;        // 4096*4
  const int b = blk >> 2;
  const int h0 = (blk & 3) << 2;     // first head of this quarter
  const short* cell = qkv + (size_t)b * S_ * 1536;
  const int t = threadIdx.x;
  // stage K,V: 25 tokens x 128 ch x 2 matrices = 800 short8 chunks
  for (int idx = t; idx < 800; idx += 256) {
    int m = idx >= 400;
    int r = idx - (m << 8) - (m << 7);  // idx - m*400 ... careful: 400 = 256+128+16
    r = idx - m * 400;
    int j = r >> 4;
    int c = (r & 15) << 3;
    *(short8*)(kv[m] + j * 128 + c) =
        *(const short8*)(cell + (size_t)j * 1536 + 512 + m * 512 + h0 * 32 + c);
  }
  __syncthreads();

  const int w = t >> 6;   // local head
  const int l = t & 63;
  int i = l >> 1;
  const int half = l & 1;
  const bool act = (i < S_);
  if (i > 24) i = 24;  // clamp for safe addressing; stores are guarded
  const int h = h0 + w;

  // q: 16 channels
  const short* qp = cell + (size_t)i * 1536 + h * HD_ + half * 16;
  float q[16];
  {
    short8 qa = *(const short8*)qp;
    short8 qb = *(const short8*)(qp + 8);
#pragma unroll
    for (int jj = 0; jj < 8; ++jj) { q[jj] = b2f(qa[jj]); q[jj + 8] = b2f(qb[jj]); }
  }
  const float scale = 0.17677669529663687f;  // 1/sqrt(32)
  const int xi = i / 5, yi = i - xi * 5;
  const int koff = w * 32 + half * 16;  // short offset within a token's 128-ch slice

  float sc[S_];
  float mx = -1e30f;
#pragma unroll
  for (int j = 0; j < S_; ++j) {
    const short* kp = kv[0] + j * 128 + koff;
    short8 ka = *(const short8*)kp;
    short8 kb = *(const short8*)(kp + 8);
    float s = 0.f;
#pragma unroll
    for (int jj = 0; jj < 8; ++jj) {
      s += q[jj] * b2f(ka[jj]);
      s += q[jj + 8] * b2f(kb[jj]);
    }
    s += __shfl_xor(s, 1);  // combine the two d-halves
    const int xj = j / 5, yj = j - xj * 5;
    const int ridx = (xi - xj + 4) * 9 + (yi - yj + 4);
    s = s * scale + bias_table[ridx * H_ + h];
    sc[j] = s;
    mx = fmaxf(mx, s);
  }
  float den = 0.f;
#pragma unroll
  for (int j = 0; j < S_; ++j) {
    float e = __expf(sc[j] - mx);
    sc[j] = e;
    den += e;
  }
  const float inv = 1.0f / den;
  float ov[16];
#pragma unroll
  for (int d = 0; d < 16; ++d) ov[d] = 0.f;
#pragma unroll
  for (int j = 0; j < S_; ++j) {
    const float pr = sc[j];
    const short* vp = kv[1] + j * 128 + koff;
    short8 va = *(const short8*)vp;
    short8 vb = *(const short8*)(vp + 8);
#pragma unroll
    for (int jj = 0; jj < 8; ++jj) {
      ov[jj] += pr * b2f(va[jj]);
      ov[jj + 8] += pr * b2f(vb[jj]);
    }
  }
  if (act) {
    short* op = o + ((size_t)b * S_ + i) * D_ + h * HD_ + half * 16;
    short8 v0, v1;
#pragma unroll
    for (int jj = 0; jj < 8; ++jj) {
      v0[jj] = f2b(ov[jj] * inv);
      v1[jj] = f2b(ov[jj + 8] * inv);
    }
    *(short8*)op = v0;
    *(short8*)(op + 8) = v1;
  }
}

// ---------------------------------------------------------------------------
// Mean-pool over S then pred head: pred[b][n] = pooled . pred_w[n] + pred_b[n]
// ---------------------------------------------------------------------------
__global__ __launch_bounds__(256) void pred_ker(const float* __restrict__ xf,
                                                const float* __restrict__ pw,
                                                const float* __restrict__ pb,
                                                float* __restrict__ pred) {
  __shared__ float pooled[D_];
  int b = blockIdx.x;
  const float* xb = xf + (size_t)b * S_ * D_;
  for (int d = threadIdx.x; d < D_; d += 256) {
    float s = 0.f;
#pragma unroll
    for (int j = 0; j < S_; ++j) s += xb[(size_t)j * D_ + d];
    pooled[d] = s * (1.0f / 25.0f);
  }
  __syncthreads();
  for (int n = threadIdx.x; n < NG_; n += 256) {
    const float* w = pw + (size_t)n * D_;
    float s = pb[n];
    for (int d = 0; d < D_; d += 4) {
      f32x4 wv = *(const f32x4*)(w + d);
      s += pooled[d] * wv[0] + pooled[d + 1] * wv[1] + pooled[d + 2] * wv[2] +
           pooled[d + 3] * wv[3];
    }
    pred[(size_t)b * NG_ + n] = s;
  }
}

// ---------------------------------------------------------------------------
extern "C" void kernel_launch(void* const* d_in, const int* in_sizes, int n_in,
                              void* d_out, int out_size, void* d_ws, size_t ws_size,
                              hipStream_t stream) {
  const float* nf = (const float*)d_in[0];
  const float* bias_table = (const float*)d_in[1];
  const float* ln1_g = (const float*)d_in[2];
  const float* ln1_b = (const float*)d_in[3];
  const float* wqkv = (const float*)d_in[4];
  const float* bqkv = (const float*)d_in[5];
  const float* wo = (const float*)d_in[6];
  const float* bo = (const float*)d_in[7];
  const float* ln2_g = (const float*)d_in[8];
  const float* ln2_b = (const float*)d_in[9];
  const float* w1 = (const float*)d_in[10];
  const float* b1 = (const float*)d_in[11];
  const float* w2 = (const float*)d_in[12];
  const float* b2 = (const float*)d_in[13];
  const float* lnf_g = (const float*)d_in[14];
  const float* lnf_b = (const float*)d_in[15];
  const float* pred_w = (const float*)d_in[16];
  const float* pred_b = (const float*)d_in[17];

  float* x = (float*)d_out;                 // residual stream lives in d_out x-region
  float* pred = x + (size_t)M_ * D_;        // [4096][250]

  char* p = (char*)d_ws;
  short* qkvb = (short*)p; p += (size_t)M_ * 1536 * 2;
  short* xnb = (short*)p;  p += (size_t)M_ * D_ * 2;
  short* ob = (short*)p;   p += (size_t)M_ * D_ * 2;
  short* hb = (short*)p;   p += (size_t)M_ * D_ * 2;
  short* wqkvb = (short*)p; p += (size_t)DEPTH_ * 1536 * 512 * 2;
  short* wob = (short*)p;   p += (size_t)DEPTH_ * 512 * 512 * 2;
  short* w1b = (short*)p;   p += (size_t)DEPTH_ * 512 * 512 * 2;
  short* w2b = (short*)p;   p += (size_t)DEPTH_ * 512 * 512 * 2;

  // weights -> bf16
  {
    int n4 = DEPTH_ * 1536 * 512 / 4;
    cvt_f2b_ker<<<(n4 + 255) / 256, 256, 0, stream>>>(wqkv, wqkvb, n4);
    n4 = DEPTH_ * 512 * 512 / 4;
    cvt_f2b_ker<<<(n4 + 255) / 256, 256, 0, stream>>>(wo, wob, n4);
    cvt_f2b_ker<<<(n4 + 255) / 256, 256, 0, stream>>>(w1, w1b, n4);
    cvt_f2b_ker<<<(n4 + 255) / 256, 256, 0, stream>>>(w2, w2b, n4);
  }

  for (int L = 0; L < DEPTH_; ++L) {
    const float* xin = (L == 0) ? nf : x;
    // LN1 -> xn (bf16)
    ln_to_bf16_ker<<<M_ / 4, 256, 0, stream>>>(xin, ln1_g + L * D_, ln1_b + L * D_, xnb);
    // qkv = xn @ wqkv^T + bqkv (bf16 out)
    gemm_bf16_ker<0><<<(1536 / 128) * (M_ / 128), 256, 0, stream>>>(
        xnb, wqkvb + (size_t)L * 1536 * 512, bqkv + (size_t)L * 1536, qkvb, nullptr,
        nullptr, 1536, 12);
    // attention -> o (bf16)
    attn_ker<<<BATCH_ * 4, 256, 0, stream>>>(qkvb, bias_table, ob);
    // x += o @ wo^T + bo   (layer 0: x = nf + o @ wo^T + bo, kills the memcpy)
    if (L == 0) {
      gemm_bf16_ker<3><<<(512 / 128) * (M_ / 128), 256, 0, stream>>>(
          ob, wob, bo, nullptr, x, nf, 512, 4);
    } else {
      gemm_bf16_ker<1><<<(512 / 128) * (M_ / 128), 256, 0, stream>>>(
          ob, wob + (size_t)L * 512 * 512, bo + (size_t)L * D_, nullptr, x, nullptr, 512, 4);
    }
    // LN2 -> xn
    ln_to_bf16_ker<<<M_ / 4, 256, 0, stream>>>(x, ln2_g + L * D_, ln2_b + L * D_, xnb);
    // h = gelu(xn @ w1^T + b1) (bf16 out)
    gemm_bf16_ker<2><<<(512 / 128) * (M_ / 128), 256, 0, stream>>>(
        xnb, w1b + (size_t)L * 512 * 512, b1 + (size_t)L * D_, hb, nullptr, nullptr, 512, 4);
    // x += h @ w2^T + b2
    gemm_bf16_ker<1><<<(512 / 128) * (M_ / 128), 256, 0, stream>>>(
        hb, w2b + (size_t)L * 512 * 512, b2 + (size_t)L * D_, nullptr, x, nullptr, 512, 4);
  }

  // final LN in place on d_out x region
  ln_f32_inplace_ker<<<M_ / 4, 256, 0, stream>>>(x, lnf_g, lnf_b);
  // pooled mean + pred head
  pred_ker<<<BATCH_, 256, 0, stream>>>(x, pred_w, pred_b, pred);
}

// Round 4
// 4092.102 us; speedup vs baseline: 1.4269x; 1.2866x over previous
//
#include <hip/hip_runtime.h>
#include <cstdint>
#include <cstddef>

#define D_ 512
#define S_ 25
#define H_ 16
#define HD_ 32
#define DEPTH_ 3
#define NG_ 250
#define BATCH_ 4096
#define M_ (BATCH_ * S_) /* 102400 */
#define EPS_ 1e-5f

typedef __attribute__((ext_vector_type(8))) short short8;
typedef __attribute__((ext_vector_type(4))) short short4v;
typedef __attribute__((ext_vector_type(4))) float f32x4;

__device__ __forceinline__ float b2f(short s) {
  union { unsigned u; float f; } c;
  c.u = ((unsigned)(unsigned short)s) << 16;
  return c.f;
}
__device__ __forceinline__ short f2b(float f) {
  union { float f; unsigned u; } c; c.f = f;
  unsigned u = c.u + 0x7FFFu + ((c.u >> 16) & 1u);
  return (short)(u >> 16);
}
__device__ __forceinline__ unsigned pkbf(float a, float b) {
  return (unsigned)(unsigned short)f2b(a) | ((unsigned)(unsigned short)f2b(b) << 16);
}

__device__ __forceinline__ void gld_lds16(const void* g, void* l) {
  __builtin_amdgcn_global_load_lds((const __attribute__((address_space(1))) void*)g,
                                   (__attribute__((address_space(3))) void*)l, 16, 0, 0);
}

// ---------------------------------------------------------------------------
// f32 -> bf16 conversion (weights), 4 elems/thread
// ---------------------------------------------------------------------------
__global__ __launch_bounds__(256) void cvt_f2b_ker(const float* __restrict__ in,
                                                   short* __restrict__ out, int n4) {
  int i = blockIdx.x * 256 + threadIdx.x;
  if (i < n4) {
    f32x4 v = *(const f32x4*)(in + (size_t)i * 4);
    short4v o;
#pragma unroll
    for (int j = 0; j < 4; ++j) o[j] = f2b(v[j]);
    *(short4v*)(out + (size_t)i * 4) = o;
  }
}

// ---------------------------------------------------------------------------
// LayerNorm: one wave per 512-row. bf16 output variant (for GEMM A input).
// ---------------------------------------------------------------------------
__global__ __launch_bounds__(256) void ln_to_bf16_ker(const float* __restrict__ x,
                                                      const float* __restrict__ g,
                                                      const float* __restrict__ bb,
                                                      short* __restrict__ out) {
  int row = (blockIdx.x << 2) + (threadIdx.x >> 6);
  int l = threadIdx.x & 63;
  const float* xr = x + (size_t)row * D_ + l * 8;
  f32x4 a = *(const f32x4*)xr;
  f32x4 b2v = *(const f32x4*)(xr + 4);
  float v[8];
#pragma unroll
  for (int j = 0; j < 4; ++j) { v[j] = a[j]; v[j + 4] = b2v[j]; }
  float s = 0.f, q = 0.f;
#pragma unroll
  for (int j = 0; j < 8; ++j) { s += v[j]; q += v[j] * v[j]; }
#pragma unroll
  for (int off = 32; off; off >>= 1) { s += __shfl_xor(s, off); q += __shfl_xor(q, off); }
  float mean = s * (1.0f / 512.0f);
  float var = q * (1.0f / 512.0f) - mean * mean;
  float rstd = rsqrtf(var + EPS_);
  const float* gp = g + l * 8;
  const float* bp = bb + l * 8;
  f32x4 g0 = *(const f32x4*)gp, g1 = *(const f32x4*)(gp + 4);
  f32x4 b0 = *(const f32x4*)bp, b1 = *(const f32x4*)(bp + 4);
  short8 o;
#pragma unroll
  for (int j = 0; j < 8; ++j) {
    float gg = (j < 4) ? g0[j] : g1[j - 4];
    float bv = (j < 4) ? b0[j] : b1[j - 4];
    o[j] = f2b((v[j] - mean) * rstd * gg + bv);
  }
  *(short8*)(out + (size_t)row * D_ + l * 8) = o;
}

// f32 in-place variant (final LN on d_out x region)
__global__ __launch_bounds__(256) void ln_f32_inplace_ker(float* __restrict__ x,
                                                          const float* __restrict__ g,
                                                          const float* __restrict__ bb) {
  int row = (blockIdx.x << 2) + (threadIdx.x >> 6);
  int l = threadIdx.x & 63;
  float* xr = x + (size_t)row * D_ + l * 8;
  f32x4 a = *(const f32x4*)xr;
  f32x4 b2v = *(const f32x4*)(xr + 4);
  float v[8];
#pragma unroll
  for (int j = 0; j < 4; ++j) { v[j] = a[j]; v[j + 4] = b2v[j]; }
  float s = 0.f, q = 0.f;
#pragma unroll
  for (int j = 0; j < 8; ++j) { s += v[j]; q += v[j] * v[j]; }
#pragma unroll
  for (int off = 32; off; off >>= 1) { s += __shfl_xor(s, off); q += __shfl_xor(q, off); }
  float mean = s * (1.0f / 512.0f);
  float var = q * (1.0f / 512.0f) - mean * mean;
  float rstd = rsqrtf(var + EPS_);
  const float* gp = g + l * 8;
  const float* bp = bb + l * 8;
  f32x4 g0 = *(const f32x4*)gp, g1 = *(const f32x4*)(gp + 4);
  f32x4 b0 = *(const f32x4*)bp, b1 = *(const f32x4*)(bp + 4);
  f32x4 o0, o1;
#pragma unroll
  for (int j = 0; j < 4; ++j) {
    o0[j] = (v[j] - mean) * rstd * g0[j] + b0[j];
    o1[j] = (v[j + 4] - mean) * rstd * g1[j] + b1[j];
  }
  *(f32x4*)xr = o0;
  *(f32x4*)(xr + 4) = o1;
}

// ---------------------------------------------------------------------------
// bf16 GEMM: out[m][n] = sum_k A[m][k] * W[n][k] + bias[n]   (K = 512 fixed)
// 128x128 tile, BK=64, 4 waves (2x2), mfma_f32_16x16x32_bf16, XOR-swizzled LDS,
// global_load_lds width-16 staging. 1-D grid + bijective XCD-chunked swizzle.
// EPI: 0 = store bf16, 1 = f32 residual add into Xres,
//      2 = exact GELU -> bf16, 3 = Xres = Xbase + v (first residual)
// ---------------------------------------------------------------------------
template <int EPI>
__global__ __launch_bounds__(256) void gemm_bf16_ker(const short* __restrict__ A,
                                                     const short* __restrict__ Bw,
                                                     const float* __restrict__ bias,
                                                     short* __restrict__ Obf,
                                                     float* __restrict__ Xres,
                                                     const float* __restrict__ Xbase,
                                                     int N, int nx) {
  constexpr int K = 512;
  __shared__ short At[128 * 64];
  __shared__ short Bt[128 * 64];
  const int tid = threadIdx.x;
  const int l = tid & 63;
  const int w = tid >> 6;
  const int wr = w >> 1, wc = w & 1;
  const int nwg = gridDim.x;
  const int orig = blockIdx.x;
  const int wg = ((orig & 7) * (nwg >> 3)) + (orig >> 3);
  const int by = wg / nx;
  const int bx = wg - by * nx;
  const int m0 = by * 128;
  const int n0 = bx * 128;

  f32x4 acc[4][4] = {};

  for (int kt = 0; kt < K; kt += 64) {
#pragma unroll
    for (int i = 0; i < 4; ++i) {
      int chunk = i * 256 + tid;
      int row = chunk >> 3;
      int colS = ((chunk & 7) << 3) ^ ((row & 7) << 3);
      const short* ga = A + (size_t)(m0 + row) * K + kt + colS;
      const short* gb = Bw + (size_t)(n0 + row) * K + kt + colS;
      int base = (i * 256 + (w << 6)) << 3;
      gld_lds16(ga, &At[base]);
      gld_lds16(gb, &Bt[base]);
    }
    __syncthreads();
#pragma unroll
    for (int kk = 0; kk < 64; kk += 32) {
      short8 af[4], bfr[4];
#pragma unroll
      for (int mi = 0; mi < 4; ++mi) {
        int row = (wr << 6) + (mi << 4) + (l & 15);
        int colS = (kk + ((l >> 4) << 3)) ^ ((row & 7) << 3);
        af[mi] = *(const short8*)&At[row * 64 + colS];
      }
#pragma unroll
      for (int ni = 0; ni < 4; ++ni) {
        int row = (wc << 6) + (ni << 4) + (l & 15);
        int colS = (kk + ((l >> 4) << 3)) ^ ((row & 7) << 3);
        bfr[ni] = *(const short8*)&Bt[row * 64 + colS];
      }
#pragma unroll
      for (int mi = 0; mi < 4; ++mi)
#pragma unroll
        for (int ni = 0; ni < 4; ++ni)
          acc[mi][ni] = __builtin_amdgcn_mfma_f32_16x16x32_bf16(af[mi], bfr[ni], acc[mi][ni], 0, 0, 0);
    }
    __syncthreads();
  }

  const int lrow = (l >> 4) << 2;
  const int lcol = l & 15;
#pragma unroll
  for (int ni = 0; ni < 4; ++ni) {
    int gn = n0 + (wc << 6) + (ni << 4) + lcol;
    float bs = bias[gn];
#pragma unroll
    for (int mi = 0; mi < 4; ++mi) {
      int gm = m0 + (wr << 6) + (mi << 4) + lrow;
#pragma unroll
      for (int r = 0; r < 4; ++r) {
        float v = acc[mi][ni][r] + bs;
        size_t idx = (size_t)(gm + r) * N + gn;
        if (EPI == 0) {
          Obf[idx] = f2b(v);
        } else if (EPI == 1) {
          Xres[idx] += v;
        } else if (EPI == 2) {
          Obf[idx] = f2b(0.5f * v * (1.0f + erff(v * 0.70710678118654752f)));
        } else {
          Xres[idx] = Xbase[idx] + v;
        }
      }
    }
  }
}

// ---------------------------------------------------------------------------
// MFMA attention. Block = 256 threads = 4 waves = 4 heads of one cell.
// Wave computes one head: S = K·Q^T (rows=key, cols=query) via 4x
// mfma_f32_16x16x32_bf16 (K=32=HD in one shot), lane-local softmax over k with
// 2 shfl_xor reductions, analytic P->A-fragment repack (8 shfl per q-tile),
// V^T B-fragments via scalar LDS column gathers, 4x PV mfma, guarded stores.
// Fragment layouts identical to the (verified working) GEMM above:
//   A/B frag: lane holds row (l&15), k = (l>>4)*8 + e (e=0..7)
//   C/D:      col = l&15, row = (l>>4)*4 + reg
// ---------------------------------------------------------------------------
__global__ __launch_bounds__(256) void attn_ker(const short* __restrict__ qkv,
                                                const float* __restrict__ bias_table,
                                                short* __restrict__ o) {
  __shared__ short Qs[4][32][40];  // rows padded to 40 shorts (80 B, 16B-aligned)
  __shared__ short Ks[4][32][40];
  __shared__ short Vs[4][32][36];  // rows padded to 36 shorts (spread banks for col-gather)

  const int blk = blockIdx.x;      // 4096 cells * 4 quarters
  const int b = blk >> 2;
  const int h0 = (blk & 3) << 2;
  const short* cell = qkv + (size_t)b * S_ * 1536;
  const int t = threadIdx.x;

  // stage Q,K rows 0..24 (short8 chunks): 2 * 4hd * 25 * 4 = 800
  for (int idx = t; idx < 800; idx += 256) {
    int m = idx >= 400;  // 0=Q, 1=K
    int r = idx - m * 400;
    int hd = r / 100;
    int rr = r - hd * 100;
    int j = rr >> 2;
    int c = rr & 3;
    short8 v = *(const short8*)(cell + (size_t)j * 1536 + m * 512 + (h0 + hd) * 32 + c * 8);
    short* dst = (m ? &Ks[hd][j][0] : &Qs[hd][j][0]) + c * 8;
    *(short8*)dst = v;
  }
  // stage V rows 0..24 (short4 chunks, rows are 8B-aligned): 4hd * 25 * 8 = 800
  for (int idx = t; idx < 800; idx += 256) {
    int hd = idx / 200;
    int rr = idx - hd * 200;
    int j = rr >> 3;
    int c = rr & 7;
    short4v v = *(const short4v*)(cell + (size_t)j * 1536 + 1024 + (h0 + hd) * 32 + c * 4);
    *(short4v*)(&Vs[hd][j][0] + c * 4) = v;
  }
  // zero V pad rows 25..31 (so P=0 rows contribute exactly 0): 4*7*9 = 252 short4
  for (int idx = t; idx < 252; idx += 256) {
    int hd = idx / 63;
    int rr = idx - hd * 63;
    int j = 25 + rr / 9;
    int c = rr - (rr / 9) * 9;
    short4v z = {};
    *(short4v*)(&Vs[hd][j][0] + c * 4) = z;
  }
  __syncthreads();

  const int w = t >> 6;
  const int l = t & 63;
  const int h = h0 + w;
  const int lane16 = l & 15;
  const int g = l >> 4;

  // ---- QK^T: S[k][q] = sum_d K[k][d] * Q[q][d]
  short8 kf[2], qf[2];
#pragma unroll
  for (int ri = 0; ri < 2; ++ri)
    kf[ri] = *(const short8*)(&Ks[w][16 * ri + lane16][g * 8]);
#pragma unroll
  for (int ci = 0; ci < 2; ++ci)
    qf[ci] = *(const short8*)(&Qs[w][16 * ci + lane16][g * 8]);

  f32x4 sc[2][2];
#pragma unroll
  for (int ri = 0; ri < 2; ++ri)
#pragma unroll
    for (int ci = 0; ci < 2; ++ci) {
      f32x4 z = {};
      sc[ri][ci] = __builtin_amdgcn_mfma_f32_16x16x32_bf16(kf[ri], qf[ci], z, 0, 0, 0);
    }

  // ---- per-query softmax + P fragments + V^T fragments + PV
  const float scale = 0.17677669529663687f;  // 1/sqrt(32)

  // V^T B-fragments: lane = col d = 16*di + lane16; k = g*8 + e
  short8 vfrag[2];
#pragma unroll
  for (int di = 0; di < 2; ++di) {
    int d = 16 * di + lane16;
#pragma unroll
    for (int e = 0; e < 8; ++e) {
      vfrag[di][e] = Vs[w][g * 8 + e][d];
    }
  }

  short8 pfrag[2];
#pragma unroll
  for (int ci = 0; ci < 2; ++ci) {
    int q = 16 * ci + lane16;
    int qc = q < 25 ? q : 24;
    int xq = qc / 5, yq = qc - xq * 5;
    float p[2][4];
    // bias add + mask (k >= 25 -> -1e30)
#pragma unroll
    for (int ri = 0; ri < 2; ++ri) {
#pragma unroll
      for (int r = 0; r < 4; ++r) {
        int k = 16 * ri + 4 * g + r;
        int kc = k < 25 ? k : 24;
        int xk = kc / 5, yk = kc - xk * 5;
        int ridx = (xq - xk + 4) * 9 + (yq - yk + 4);
        float bsv = bias_table[ridx * H_ + h];
        float v = sc[ri][ci][r] * scale + bsv;
        p[ri][r] = (k < 25) ? v : -1e30f;
      }
    }
    // max over k: own 8 -> cross 4 lane-groups
    float mx = p[0][0];
#pragma unroll
    for (int ri = 0; ri < 2; ++ri)
#pragma unroll
      for (int r = 0; r < 4; ++r) mx = fmaxf(mx, p[ri][r]);
    mx = fmaxf(mx, __shfl_xor(mx, 16));
    mx = fmaxf(mx, __shfl_xor(mx, 32));
    // exp + denominator
    float den = 0.f;
#pragma unroll
    for (int ri = 0; ri < 2; ++ri)
#pragma unroll
      for (int r = 0; r < 4; ++r) {
        float e = __expf(p[ri][r] - mx);
        p[ri][r] = e;
        den += e;
      }
    den += __shfl_xor(den, 16);
    den += __shfl_xor(den, 32);
    float inv = 1.0f / den;
#pragma unroll
    for (int ri = 0; ri < 2; ++ri)
#pragma unroll
      for (int r = 0; r < 4; ++r) p[ri][r] *= inv;

    // pack: W[ri][0] = (p0,p1), W[ri][1] = (p2,p3)
    unsigned W00 = pkbf(p[0][0], p[0][1]);
    unsigned W01 = pkbf(p[0][2], p[0][3]);
    unsigned W10 = pkbf(p[1][0], p[1][1]);
    unsigned W11 = pkbf(p[1][2], p[1][3]);
    // A-frag repack: target lane (lane16, g), element e: k = 8g+e ->
    //   ri = g>>1, src group = 2(g&1) + (e>>2), reg = e&3
    int sl = lane16 + 32 * (g & 1);
    int sel = g >> 1;
    unsigned y0a = (unsigned)__shfl((int)W00, sl);
    unsigned y0b = (unsigned)__shfl((int)W10, sl);
    unsigned w0 = sel ? y0b : y0a;
    unsigned y1a = (unsigned)__shfl((int)W01, sl);
    unsigned y1b = (unsigned)__shfl((int)W11, sl);
    unsigned w1 = sel ? y1b : y1a;
    unsigned y2a = (unsigned)__shfl((int)W00, sl + 16);
    unsigned y2b = (unsigned)__shfl((int)W10, sl + 16);
    unsigned w2 = sel ? y2b : y2a;
    unsigned y3a = (unsigned)__shfl((int)W01, sl + 16);
    unsigned y3b = (unsigned)__shfl((int)W11, sl + 16);
    unsigned w3 = sel ? y3b : y3a;
    short8 f;
    f[0] = (short)(w0 & 0xffff); f[1] = (short)(w0 >> 16);
    f[2] = (short)(w1 & 0xffff); f[3] = (short)(w1 >> 16);
    f[4] = (short)(w2 & 0xffff); f[5] = (short)(w2 >> 16);
    f[6] = (short)(w3 & 0xffff); f[7] = (short)(w3 >> 16);
    pfrag[ci] = f;
  }

  // ---- PV: O[q][d] = sum_k P[q][k] V[k][d]
  f32x4 ot[2][2];
#pragma unroll
  for (int qi = 0; qi < 2; ++qi)
#pragma unroll
    for (int di = 0; di < 2; ++di) {
      f32x4 z = {};
      ot[qi][di] = __builtin_amdgcn_mfma_f32_16x16x32_bf16(pfrag[qi], vfrag[di], z, 0, 0, 0);
    }

  // ---- store (rows q = 16*qi + 4g + r, cols d = 16*di + lane16)
#pragma unroll
  for (int qi = 0; qi < 2; ++qi) {
#pragma unroll
    for (int r = 0; r < 4; ++r) {
      int q = 16 * qi + 4 * g + r;
      if (q < 25) {
        short* op = o + ((size_t)b * S_ + q) * D_ + h * HD_;
#pragma unroll
        for (int di = 0; di < 2; ++di) {
          op[16 * di + lane16] = f2b(ot[qi][di][r]);
        }
      }
    }
  }
}

// ---------------------------------------------------------------------------
// Mean-pool over S then pred head: pred[b][n] = pooled . pred_w[n] + pred_b[n]
// ---------------------------------------------------------------------------
__global__ __launch_bounds__(256) void pred_ker(const float* __restrict__ xf,
                                                const float* __restrict__ pw,
                                                const float* __restrict__ pb,
                                                float* __restrict__ pred) {
  __shared__ float pooled[D_];
  int b = blockIdx.x;
  const float* xb = xf + (size_t)b * S_ * D_;
  for (int d = threadIdx.x; d < D_; d += 256) {
    float s = 0.f;
#pragma unroll
    for (int j = 0; j < S_; ++j) s += xb[(size_t)j * D_ + d];
    pooled[d] = s * (1.0f / 25.0f);
  }
  __syncthreads();
  for (int n = threadIdx.x; n < NG_; n += 256) {
    const float* w = pw + (size_t)n * D_;
    float s = pb[n];
    for (int d = 0; d < D_; d += 4) {
      f32x4 wv = *(const f32x4*)(w + d);
      s += pooled[d] * wv[0] + pooled[d + 1] * wv[1] + pooled[d + 2] * wv[2] +
           pooled[d + 3] * wv[3];
    }
    pred[(size_t)b * NG_ + n] = s;
  }
}

// ---------------------------------------------------------------------------
extern "C" void kernel_launch(void* const* d_in, const int* in_sizes, int n_in,
                              void* d_out, int out_size, void* d_ws, size_t ws_size,
                              hipStream_t stream) {
  const float* nf = (const float*)d_in[0];
  const float* bias_table = (const float*)d_in[1];
  const float* ln1_g = (const float*)d_in[2];
  const float* ln1_b = (const float*)d_in[3];
  const float* wqkv = (const float*)d_in[4];
  const float* bqkv = (const float*)d_in[5];
  const float* wo = (const float*)d_in[6];
  const float* bo = (const float*)d_in[7];
  const float* ln2_g = (const float*)d_in[8];
  const float* ln2_b = (const float*)d_in[9];
  const float* w1 = (const float*)d_in[10];
  const float* b1 = (const float*)d_in[11];
  const float* w2 = (const float*)d_in[12];
  const float* b2 = (const float*)d_in[13];
  const float* lnf_g = (const float*)d_in[14];
  const float* lnf_b = (const float*)d_in[15];
  const float* pred_w = (const float*)d_in[16];
  const float* pred_b = (const float*)d_in[17];

  float* x = (float*)d_out;
  float* pred = x + (size_t)M_ * D_;

  char* p = (char*)d_ws;
  short* qkvb = (short*)p; p += (size_t)M_ * 1536 * 2;
  short* xnb = (short*)p;  p += (size_t)M_ * D_ * 2;
  short* ob = (short*)p;   p += (size_t)M_ * D_ * 2;
  short* hb = (short*)p;   p += (size_t)M_ * D_ * 2;
  short* wqkvb = (short*)p; p += (size_t)DEPTH_ * 1536 * 512 * 2;
  short* wob = (short*)p;   p += (size_t)DEPTH_ * 512 * 512 * 2;
  short* w1b = (short*)p;   p += (size_t)DEPTH_ * 512 * 512 * 2;
  short* w2b = (short*)p;   p += (size_t)DEPTH_ * 512 * 512 * 2;

  {
    int n4 = DEPTH_ * 1536 * 512 / 4;
    cvt_f2b_ker<<<(n4 + 255) / 256, 256, 0, stream>>>(wqkv, wqkvb, n4);
    n4 = DEPTH_ * 512 * 512 / 4;
    cvt_f2b_ker<<<(n4 + 255) / 256, 256, 0, stream>>>(wo, wob, n4);
    cvt_f2b_ker<<<(n4 + 255) / 256, 256, 0, stream>>>(w1, w1b, n4);
    cvt_f2b_ker<<<(n4 + 255) / 256, 256, 0, stream>>>(w2, w2b, n4);
  }

  for (int L = 0; L < DEPTH_; ++L) {
    const float* xin = (L == 0) ? nf : x;
    ln_to_bf16_ker<<<M_ / 4, 256, 0, stream>>>(xin, ln1_g + L * D_, ln1_b + L * D_, xnb);
    gemm_bf16_ker<0><<<(1536 / 128) * (M_ / 128), 256, 0, stream>>>(
        xnb, wqkvb + (size_t)L * 1536 * 512, bqkv + (size_t)L * 1536, qkvb, nullptr,
        nullptr, 1536, 12);
    attn_ker<<<BATCH_ * 4, 256, 0, stream>>>(qkvb, bias_table, ob);
    if (L == 0) {
      gemm_bf16_ker<3><<<(512 / 128) * (M_ / 128), 256, 0, stream>>>(
          ob, wob, bo, nullptr, x, nf, 512, 4);
    } else {
      gemm_bf16_ker<1><<<(512 / 128) * (M_ / 128), 256, 0, stream>>>(
          ob, wob + (size_t)L * 512 * 512, bo + (size_t)L * D_, nullptr, x, nullptr, 512, 4);
    }
    ln_to_bf16_ker<<<M_ / 4, 256, 0, stream>>>(x, ln2_g + L * D_, ln2_b + L * D_, xnb);
    gemm_bf16_ker<2><<<(512 / 128) * (M_ / 128), 256, 0, stream>>>(
        xnb, w1b + (size_t)L * 512 * 512, b1 + (size_t)L * D_, hb, nullptr, nullptr, 512, 4);
    gemm_bf16_ker<1><<<(512 / 128) * (M_ / 128), 256, 0, stream>>>(
        hb, w2b + (size_t)L * 512 * 512, b2 + (size_t)L * D_, nullptr, x, nullptr, 512, 4);
  }

  ln_f32_inplace_ker<<<M_ / 4, 256, 0, stream>>>(x, lnf_g, lnf_b);
  pred_ker<<<BATCH_, 256, 0, stream>>>(x, pred_w, pred_b, pred);
}